// Round 1
// baseline (178.125 us; speedup 1.0000x reference)
//
#include <hip/hip_runtime.h>
#include <math.h>

#define BB 64
#define TT 512
#define DD 256
#define CC 20
#define SS 32            // segments per batch element
#define LL 16            // production steps per segment
#define WW 16            // warm-up steps (Birkhoff contraction ~0.34^16 ~ 3e-8)
#define PR 20            // prob row stride (floats)
#define NSEG (BB * SS)   // 2048 vector chains
#define LN_EPS 1e-5f

__device__ __forceinline__ float dpp_sum16(float v) {
  v += __int_as_float(__builtin_amdgcn_update_dpp(0, __float_as_int(v), 0xB1, 0xF, 0xF, true));
  v += __int_as_float(__builtin_amdgcn_update_dpp(0, __float_as_int(v), 0x4E, 0xF, 0xF, true));
  v += __int_as_float(__builtin_amdgcn_update_dpp(0, __float_as_int(v), 0x141, 0xF, 0xF, true));
  v += __int_as_float(__builtin_amdgcn_update_dpp(0, __float_as_int(v), 0x140, 0xF, 0xF, true));
  return v;
}
__device__ __forceinline__ float dpp_max16(float v) {
  v = fmaxf(v, __int_as_float(__builtin_amdgcn_update_dpp(0, __float_as_int(v), 0xB1, 0xF, 0xF, true)));
  v = fmaxf(v, __int_as_float(__builtin_amdgcn_update_dpp(0, __float_as_int(v), 0x4E, 0xF, 0xF, true)));
  v = fmaxf(v, __int_as_float(__builtin_amdgcn_update_dpp(0, __float_as_int(v), 0x141, 0xF, 0xF, true)));
  v = fmaxf(v, __int_as_float(__builtin_amdgcn_update_dpp(0, __float_as_int(v), 0x140, 0xF, 0xF, true)));
  return v;
}
__device__ __forceinline__ float wave_reduce_sum64(float v) {
  #pragma unroll
  for (int off = 32; off > 0; off >>= 1) v += __shfl_xor(v, off, 64);
  return v;
}
__device__ __forceinline__ float wave_reduce_max64(float v) {
  #pragma unroll
  for (int off = 32; off > 0; off >>= 1) v = fmaxf(v, __shfl_xor(v, off, 64));
  return v;
}

// ---- Kernel A: emb gather + LN + linear + softmax probs + gold contribution ----
// 16 lanes per token, 16 tokens per 256-thread block, grid 2048.
// Block covers t in [ (blk%32)*16, +16 ) of b = blk/32 -> early exit for
// padding blocks (avg ~half). Also emits the FULL per-token gold contribution
// (emit + trans + start/end) so combine never does scattered loads.
__global__ __launch_bounds__(256, 1) void token_probs_kernel(
    const int* __restrict__ words, const float* __restrict__ emb,
    const float* __restrict__ ln_g, const float* __restrict__ ln_b,
    const float* __restrict__ W, const float* __restrict__ bias,
    const int* __restrict__ seq_len, const int* __restrict__ target,
    const float* __restrict__ trans, const float* __restrict__ startv,
    const float* __restrict__ endv,
    float* __restrict__ probs, float* __restrict__ goldEmit)
{
  int b = blockIdx.x >> 5;
  int t0 = (blockIdx.x & 31) << 4;
  int len = seq_len[b];
  if (t0 >= len) return;                       // whole block is padding

  __shared__ __align__(16) float4 sW4[64 * 21];  // [d4][c], stride 21
  __shared__ float sb[CC];
  int tid = threadIdx.x;
  for (int ei = tid; ei < 64 * CC; ei += 256) {
    int d4 = ei / CC, c = ei - d4 * CC;
    int base = 4 * d4 * CC + c;  // W is (D, C) row-major
    sW4[d4 * 21 + c] = make_float4(W[base], W[base + CC], W[base + 2 * CC], W[base + 3 * CC]);
  }
  if (tid < CC) sb[tid] = bias[tid];
  __syncthreads();

  int l = tid & 15;
  int t = t0 + (tid >> 4);
  if (t >= len) return;                        // padding tail inside block
  int token = (b << 9) + t;

  int word = words[token];
  const float4* row = (const float4*)(emb + (size_t)word * DD);
  float4 x0 = row[l], x1 = row[l + 16], x2 = row[l + 32], x3 = row[l + 48];

  float4 g0 = ((const float4*)ln_g)[l];
  float4 g1 = ((const float4*)ln_g)[l + 16];
  float4 g2 = ((const float4*)ln_g)[l + 32];
  float4 g3 = ((const float4*)ln_g)[l + 48];
  float4 e0v = ((const float4*)ln_b)[l];
  float4 e1v = ((const float4*)ln_b)[l + 16];
  float4 e2v = ((const float4*)ln_b)[l + 32];
  float4 e3v = ((const float4*)ln_b)[l + 48];

  float s1 = (x0.x + x0.y) + (x0.z + x0.w) + (x1.x + x1.y) + (x1.z + x1.w)
           + (x2.x + x2.y) + (x2.z + x2.w) + (x3.x + x3.y) + (x3.z + x3.w);
  float s2 = x0.x*x0.x + x0.y*x0.y + x0.z*x0.z + x0.w*x0.w
           + x1.x*x1.x + x1.y*x1.y + x1.z*x1.z + x1.w*x1.w
           + x2.x*x2.x + x2.y*x2.y + x2.z*x2.z + x2.w*x2.w
           + x3.x*x3.x + x3.y*x3.y + x3.z*x3.z + x3.w*x3.w;
  s1 = dpp_sum16(s1);
  s2 = dpp_sum16(s2);
  float mu = s1 * (1.f / DD);
  float var = s2 * (1.f / DD) - mu * mu;
  float rr = rsqrtf(var + LN_EPS);

  x0.x = (x0.x - mu) * rr * g0.x + e0v.x;  x0.y = (x0.y - mu) * rr * g0.y + e0v.y;
  x0.z = (x0.z - mu) * rr * g0.z + e0v.z;  x0.w = (x0.w - mu) * rr * g0.w + e0v.w;
  x1.x = (x1.x - mu) * rr * g1.x + e1v.x;  x1.y = (x1.y - mu) * rr * g1.y + e1v.y;
  x1.z = (x1.z - mu) * rr * g1.z + e1v.z;  x1.w = (x1.w - mu) * rr * g1.w + e1v.w;
  x2.x = (x2.x - mu) * rr * g2.x + e2v.x;  x2.y = (x2.y - mu) * rr * g2.y + e2v.y;
  x2.z = (x2.z - mu) * rr * g2.z + e2v.z;  x2.w = (x2.w - mu) * rr * g2.w + e2v.w;
  x3.x = (x3.x - mu) * rr * g3.x + e3v.x;  x3.y = (x3.y - mu) * rr * g3.y + e3v.y;
  x3.z = (x3.z - mu) * rr * g3.z + e3v.z;  x3.w = (x3.w - mu) * rr * g3.w + e3v.w;

  int tgt = target[token];
  float f0 = 0.f, f1 = 0.f;  // lane l holds feat_l; lanes 0..3 also feat_{16+l}
  float ftgt = 0.f;          // contribution toward feats[tgt] (one lane nonzero)
  #pragma unroll
  for (int c = 0; c < CC; ++c) {
    float4 w0 = sW4[l * 21 + c];
    float4 w1 = sW4[(l + 16) * 21 + c];
    float4 w2 = sW4[(l + 32) * 21 + c];
    float4 w3 = sW4[(l + 48) * 21 + c];
    float pp = (x0.x*w0.x + x0.y*w0.y) + (x0.z*w0.z + x0.w*w0.w)
             + (x1.x*w1.x + x1.y*w1.y) + (x1.z*w1.z + x1.w*w1.w)
             + (x2.x*w2.x + x2.y*w2.y) + (x2.z*w2.z + x2.w*w2.w)
             + (x3.x*w3.x + x3.y*w3.y) + (x3.z*w3.z + x3.w*w3.w);
    pp = dpp_sum16(pp) + sb[c];
    if (c < 16) { if (l == c) f0 = pp; }
    else        { if (l == c - 16) f1 = pp; }
    if (c < 16) { if (l == c && tgt == c) ftgt = pp; }
    else        { if (l == c - 16 && tgt == c) ftgt = pp; }
  }

  float m = f0;
  if (l < 4) m = fmaxf(m, f1);
  m = dpp_max16(m);
  float q0 = __expf(f0 - m);
  float q1 = (l < 4) ? __expf(f1 - m) : 0.f;
  float ssum = dpp_sum16(q0 + q1);
  float inv = 1.0f / ssum;
  float lsm = m + __logf(ssum);
  ftgt = dpp_sum16(ftgt);      // broadcast feats[tgt] to all 16 lanes

  float* pt = probs + (size_t)token * PR;
  pt[l] = q0 * inv;
  if (l < 4) pt[16 + l] = q1 * inv;

  if (l == 0) {
    float g = ftgt - lsm;
    if (t > 0) g += trans[target[token - 1] * CC + tgt];
    else       g += startv[tgt];
    if (t == len - 1) g += endv[tgt];
    goldEmit[token] = g;
  }
}

// ---- Kernel A2: warm-restart VECTOR chains (no matrices). ----
__global__ __launch_bounds__(64, 1) void segment_kernel(
    const float* __restrict__ probs, const int* __restrict__ seq_len,
    const float* __restrict__ trans, const float* __restrict__ startv,
    float* __restrict__ partialZ, float* __restrict__ finalA)
{
  int tid = threadIdx.x;
  int grp = tid / 20;           // 0..2 active, 3 idle
  int l = tid - grp * 20;
  int chain = blockIdx.x * 3 + grp;
  bool act = (grp < 3) && (chain < NSEG);
  int ch = act ? chain : 0;
  int b = ch >> 5;              // SS = 32
  int s = ch & (SS - 1);
  int len = seq_len[b];
  int base = act ? grp * 20 : 0;

  int prod_start = s * LL + 1;
  int prod_end   = min(s * LL + LL, len - 1);
  bool empty = prod_start > prod_end;

  // fast path: every chain in this block is empty -> write zeros, exit
  if (__ballot(act && !empty) == 0ull) {
    if (act && l == 0) partialZ[ch] = 0.f;
    return;
  }

  // E column l in registers: E_i = exp(trans[i][l])
  float E0  = __expf(trans[0*CC + l]),  E1  = __expf(trans[1*CC + l]);
  float E2  = __expf(trans[2*CC + l]),  E3  = __expf(trans[3*CC + l]);
  float E4  = __expf(trans[4*CC + l]),  E5  = __expf(trans[5*CC + l]);
  float E6  = __expf(trans[6*CC + l]),  E7  = __expf(trans[7*CC + l]);
  float E8  = __expf(trans[8*CC + l]),  E9  = __expf(trans[9*CC + l]);
  float E10 = __expf(trans[10*CC + l]), E11 = __expf(trans[11*CC + l]);
  float E12 = __expf(trans[12*CC + l]), E13 = __expf(trans[13*CC + l]);
  float E14 = __expf(trans[14*CC + l]), E15 = __expf(trans[15*CC + l]);
  float E16 = __expf(trans[16*CC + l]), E17 = __expf(trans[17*CC + l]);
  float E18 = __expf(trans[18*CC + l]), E19 = __expf(trans[19*CC + l]);

  const float* pb = probs + (size_t)b * TT * PR + l;

  float v = (s == 0) ? pb[0] * __expf(startv[l]) : 1.0f;

#define STEP(t) do {                                            \
    float pr = pb[(t) * PR];                                    \
    float a0, a1, a2, a3;                                       \
    a0  = __shfl(v, base + 0, 64) * E0;                         \
    a1  = __shfl(v, base + 1, 64) * E1;                         \
    a2  = __shfl(v, base + 2, 64) * E2;                         \
    a3  = __shfl(v, base + 3, 64) * E3;                         \
    a0 += __shfl(v, base + 4, 64) * E4;                         \
    a1 += __shfl(v, base + 5, 64) * E5;                         \
    a2 += __shfl(v, base + 6, 64) * E6;                         \
    a3 += __shfl(v, base + 7, 64) * E7;                         \
    a0 += __shfl(v, base + 8, 64) * E8;                         \
    a1 += __shfl(v, base + 9, 64) * E9;                         \
    a2 += __shfl(v, base + 10, 64) * E10;                       \
    a3 += __shfl(v, base + 11, 64) * E11;                       \
    a0 += __shfl(v, base + 12, 64) * E12;                       \
    a1 += __shfl(v, base + 13, 64) * E13;                       \
    a2 += __shfl(v, base + 14, 64) * E14;                       \
    a3 += __shfl(v, base + 15, 64) * E15;                       \
    a0 += __shfl(v, base + 16, 64) * E16;                       \
    a1 += __shfl(v, base + 17, 64) * E17;                       \
    a2 += __shfl(v, base + 18, 64) * E18;                       \
    a3 += __shfl(v, base + 19, 64) * E19;                       \
    v = ((a0 + a1) + (a2 + a3)) * pr;                           \
  } while (0)

  int nwarm = (s == 0 || empty) ? 0 : WW;
  for (int t = prod_start - nwarm; t < prod_start; ++t) STEP(t);

  __shared__ float sv[64];
  sv[tid] = v;
  __syncthreads();
  float Smid = 0.f;
  #pragma unroll
  for (int i = 0; i < CC; ++i) Smid += sv[base + i];
  __syncthreads();

  if (!empty) {
    for (int t = prod_start; t <= prod_end; ++t) STEP(t);
  }
#undef STEP

  sv[tid] = v;
  __syncthreads();
  float Send = 0.f;
  #pragma unroll
  for (int i = 0; i < CC; ++i) Send += sv[base + i];

  if (act) {
    float pz;
    if (empty)       pz = 0.f;
    else if (s == 0) pz = __logf(Send);               // includes initial mass
    else             pz = __logf(Send) - __logf(Smid);
    if (l == 0) partialZ[ch] = pz;
    if (!empty && s == (len - 2) / LL)
      finalA[b * CC + l] = v / Send;                  // normalized alpha at len-1
  }
}

// ---- Kernel B: coalesced gold sum + partialZ sum + final lse. ----
__global__ __launch_bounds__(64, 1) void combine_kernel(
    const float* __restrict__ probs, const float* __restrict__ partialZ,
    const float* __restrict__ finalA, const float* __restrict__ goldEmit,
    const int* __restrict__ seq_len, const float* __restrict__ startv,
    const float* __restrict__ endv, float* __restrict__ nll)
{
  int b = blockIdx.x;
  int j = threadIdx.x;
  int len = seq_len[b];

  float gsum = 0.f;
  const float* ge = goldEmit + ((size_t)b << 9);
  for (int t = j; t < len; t += 64) gsum += ge[t];
  gsum = wave_reduce_sum64(gsum);

  float Z;
  if (len == 1) {
    const float* pb = probs + (size_t)b * TT * PR;
    float val = (j < CC) ? __logf(pb[j]) + startv[j] + endv[j] : -INFINITY;
    float m = wave_reduce_max64(val);
    float ssum = wave_reduce_sum64((j < CC) ? __expf(val - m) : 0.f);
    Z = m + __logf(ssum);
  } else {
    float pz = (j < SS) ? partialZ[b * SS + j] : 0.f;
    pz = wave_reduce_sum64(pz);
    float ve = (j < CC) ? finalA[b * CC + j] * __expf(endv[j]) : 0.f;
    float ssum = wave_reduce_sum64(ve);
    Z = pz + __logf(ssum);
  }

  if (j == 0) nll[b] = Z - gsum;
}

// ---- Kernel C: mean over B (writes out directly; no memset needed) ----
__global__ __launch_bounds__(64) void mean_kernel(
    const float* __restrict__ nll, float* __restrict__ out)
{
  float v = nll[threadIdx.x];
  v = wave_reduce_sum64(v);
  if (threadIdx.x == 0) out[0] = v * (1.0f / BB);
}

extern "C" void kernel_launch(void* const* d_in, const int* in_sizes, int n_in,
                              void* d_out, int out_size, void* d_ws, size_t ws_size,
                              hipStream_t stream) {
  const int*   words   = (const int*)d_in[0];
  const int*   seq_len = (const int*)d_in[1];
  const int*   target  = (const int*)d_in[2];
  const float* emb     = (const float*)d_in[3];
  const float* ln_g    = (const float*)d_in[4];
  const float* ln_b    = (const float*)d_in[5];
  const float* W       = (const float*)d_in[6];
  const float* bias    = (const float*)d_in[7];
  const float* trans   = (const float*)d_in[8];
  const float* startv  = (const float*)d_in[9];
  const float* endv    = (const float*)d_in[10];

  float* probs    = (float*)d_ws;                          // 655,360 floats
  float* goldEmit = probs + (size_t)BB * TT * PR;          // 32,768
  float* partialZ = goldEmit + (size_t)BB * TT;            // 2,048
  float* finalA   = partialZ + NSEG;                       // 1,280
  float* nll      = finalA + BB * CC;                      // 64
  float* out      = (float*)d_out;

  token_probs_kernel<<<2048, 256, 0, stream>>>(words, emb, ln_g, ln_b, W, bias,
                                               seq_len, target, trans, startv,
                                               endv, probs, goldEmit);
  segment_kernel<<<(NSEG + 2) / 3, 64, 0, stream>>>(probs, seq_len, trans,
                                                    startv, partialZ, finalA);
  combine_kernel<<<BB, 64, 0, stream>>>(probs, partialZ, finalA, goldEmit,
                                        seq_len, startv, endv, nll);
  mean_kernel<<<1, 64, 0, stream>>>(nll, out);
}